// Round 1
// baseline (197.647 us; speedup 1.0000x reference)
//
#include <hip/hip_runtime.h>
#include <cstddef>

// Problem constants
#define B_TOT   256
#define IN_CAPS 1152
#define KDIM    8
#define NJ      10
#define ND      16
#define JD      160           // NJ*ND

// Tiling
#define BB      4             // batches per block (W register reuse factor)
#define ISPLIT  4             // i-range splits -> grid = (256/BB)*ISPLIT = 256 blocks
#define CI      32            // i chunk per LDS stage
#define IPAR    16            // i-parallel thread groups
#define NTHREADS 640          // IPAR * NJ * 4 (d-quads)
#define IRANGE  (IN_CAPS/ISPLIT)   // 288
#define NCHUNK  (IRANGE/CI)        // 9

__device__ __forceinline__ float dot4(float4 a, float4 b) {
    return a.x*b.x + a.y*b.y + a.z*b.z + a.w*b.w;
}

// One routing iteration: s[b,j,d] = sum_i c[b,i,j] * u_hat[b,i,j,d]
// u_hat recomputed on the fly from x (LDS) and W (global, L2-resident per XCD).
// For !FIRST, c = softmax_j( u_hat[b,i,:,:] . vsum[b,:,:] ) using linearity of
// the agreement update in v.
template<bool FIRST>
__global__ __launch_bounds__(NTHREADS)
void iter_kernel(const float* __restrict__ x, const float* __restrict__ Wt,
                 const float* __restrict__ vsum, float* __restrict__ s_out)
{
    const int g   = blockIdx.x >> 2;       // b-group 0..63
    const int isp = blockIdx.x & 3;        // i-split 0..3 (XCD round-robin keeps W/4 L2-resident)
    const int b0  = g * BB;
    const int i_begin = isp * IRANGE;

    const int t = threadIdx.x;
    const int i_par = t / 40;              // 0..15
    const int r  = t - i_par * 40;
    const int j  = r >> 2;                 // 0..9
    const int dq = r & 3;                  // 0..3  (owns d = dq*4..dq*4+3)

    __shared__ float x_lds[BB][CI][KDIM];      // 4 KB
    __shared__ float logit_lds[BB][CI][NJ];    // 5 KB
    __shared__ float c_lds[BB][CI][NJ];        // 5 KB
    __shared__ float s_lds[BB][JD];            // 2.5 KB

    float4 vs[BB];
    if (!FIRST) {
        #pragma unroll
        for (int bb = 0; bb < BB; ++bb)
            vs[bb] = *(const float4*)(vsum + (size_t)(b0 + bb) * JD + j * ND + dq * 4);
    }

    float4 s_acc[BB];
    #pragma unroll
    for (int bb = 0; bb < BB; ++bb) s_acc[bb] = make_float4(0.f, 0.f, 0.f, 0.f);

    for (int c = 0; c < NCHUNK; ++c) {
        const int ib = i_begin + c * CI;

        // stage x[b0..b0+3][ib..ib+31][0..7] into LDS (256 float4, coalesced)
        if (t < (BB * CI * KDIM) / 4) {
            int bb = t >> 6;
            int f  = t & 63;
            const float4* src = (const float4*)(x + (size_t)(b0 + bb) * IN_CAPS * KDIM
                                                  + (size_t)ib * KDIM);
            ((float4*)&x_lds[bb][0][0])[f] = src[f];
        }
        __syncthreads();

        // phase 1: compute u_hat fragments in registers (+ logits if !FIRST)
        float4 u[2][BB];
        #pragma unroll
        for (int ii = 0; ii < 2; ++ii) {
            const int i_loc = i_par * 2 + ii;
            const int i = ib + i_loc;
            const float* wrow = Wt + (size_t)(i * NJ + j) * KDIM * ND + dq * 4;
            #pragma unroll
            for (int bb = 0; bb < BB; ++bb) u[ii][bb] = make_float4(0.f, 0.f, 0.f, 0.f);
            #pragma unroll
            for (int k = 0; k < KDIM; ++k) {
                float4 w4 = *(const float4*)(wrow + k * ND);   // reused across 4 batches
                #pragma unroll
                for (int bb = 0; bb < BB; ++bb) {
                    float xv = x_lds[bb][i_loc][k];            // LDS broadcast
                    u[ii][bb].x += xv * w4.x;
                    u[ii][bb].y += xv * w4.y;
                    u[ii][bb].z += xv * w4.z;
                    u[ii][bb].w += xv * w4.w;
                }
            }
            if (!FIRST) {
                #pragma unroll
                for (int bb = 0; bb < BB; ++bb) {
                    float lg = dot4(u[ii][bb], vs[bb]);
                    lg += __shfl_xor(lg, 1);   // reduce over the 4-lane d-quad group
                    lg += __shfl_xor(lg, 2);
                    if (dq == 0) logit_lds[bb][i_loc][j] = lg;
                }
            }
        }

        if (FIRST) {
            // uniform c: just accumulate (premultiplied by 0.1 at the end)
            #pragma unroll
            for (int ii = 0; ii < 2; ++ii)
                #pragma unroll
                for (int bb = 0; bb < BB; ++bb) {
                    s_acc[bb].x += u[ii][bb].x;
                    s_acc[bb].y += u[ii][bb].y;
                    s_acc[bb].z += u[ii][bb].z;
                    s_acc[bb].w += u[ii][bb].w;
                }
            __syncthreads();   // protect x_lds before next chunk's staging
        } else {
            __syncthreads();
            // phase 2: softmax over j for each (bb, i_loc); 1280 entries / 640 threads
            for (int e = t; e < BB * CI * NJ; e += NTHREADS) {
                int bb  = e / (CI * NJ);
                int rem = e - bb * (CI * NJ);
                int il  = rem / NJ;
                int jj  = rem - il * NJ;
                float m = -1e30f;
                #pragma unroll
                for (int q = 0; q < NJ; ++q) m = fmaxf(m, logit_lds[bb][il][q]);
                float ssum = 0.f;
                #pragma unroll
                for (int q = 0; q < NJ; ++q) ssum += __expf(logit_lds[bb][il][q] - m);
                c_lds[bb][il][jj] = __expf(logit_lds[bb][il][jj] - m) / ssum;
            }
            __syncthreads();
            // phase 3: s += c * u_hat (u_hat still in registers)
            #pragma unroll
            for (int ii = 0; ii < 2; ++ii) {
                const int i_loc = i_par * 2 + ii;
                #pragma unroll
                for (int bb = 0; bb < BB; ++bb) {
                    float cc = c_lds[bb][i_loc][j];
                    s_acc[bb].x += cc * u[ii][bb].x;
                    s_acc[bb].y += cc * u[ii][bb].y;
                    s_acc[bb].z += cc * u[ii][bb].z;
                    s_acc[bb].w += cc * u[ii][bb].w;
                }
            }
        }
    }

    // block-level reduction over i_par groups via LDS, then one global atomic each
    ((float*)s_lds)[t] = 0.f;   // NTHREADS == BB*JD
    __syncthreads();
    const float premul = FIRST ? 0.1f : 1.0f;   // softmax(zeros) over 10 caps = 0.1
    #pragma unroll
    for (int bb = 0; bb < BB; ++bb) {
        atomicAdd(&s_lds[bb][j * ND + dq * 4 + 0], s_acc[bb].x * premul);
        atomicAdd(&s_lds[bb][j * ND + dq * 4 + 1], s_acc[bb].y * premul);
        atomicAdd(&s_lds[bb][j * ND + dq * 4 + 2], s_acc[bb].z * premul);
        atomicAdd(&s_lds[bb][j * ND + dq * 4 + 3], s_acc[bb].w * premul);
    }
    __syncthreads();
    {
        int bb = t / JD;
        int jd = t - bb * JD;
        unsafeAtomicAdd(&s_out[(size_t)(b0 + bb) * JD + jd], s_lds[bb][jd]);
    }
}

// squash per (b,j): v = s * s2/(1+s2)/sqrt(s2+eps); 16-lane shuffle reduction.
// mode 0: vsum += v (and re-zero s for next routing iteration)
// mode 1: out = v (final)
__global__ __launch_bounds__(256)
void squash_kernel(float* __restrict__ s, float* __restrict__ vsum,
                   float* __restrict__ out, int mode)
{
    int idx = blockIdx.x * 256 + threadIdx.x;   // grid 160 -> exactly 40960
    float sv = s[idx];
    float sq = sv * sv;
    sq += __shfl_xor(sq, 1);
    sq += __shfl_xor(sq, 2);
    sq += __shfl_xor(sq, 4);
    sq += __shfl_xor(sq, 8);    // sum over the 16 d-lanes (16-aligned in wave)
    float scale = sq / (1.0f + sq) / sqrtf(sq + 1e-7f);
    float v = sv * scale;
    if (mode == 0) vsum[idx] += v;
    else           out[idx]  = v;
    s[idx] = 0.f;               // re-zero accumulator for the next iteration
}

extern "C" void kernel_launch(void* const* d_in, const int* in_sizes, int n_in,
                              void* d_out, int out_size, void* d_ws, size_t ws_size,
                              hipStream_t stream)
{
    const float* x  = (const float*)d_in[0];   // [256,1152,8]
    const float* Wt = (const float*)d_in[1];   // [1152,10,8,16]
    float* out  = (float*)d_out;               // [256,10,16]
    float* s    = (float*)d_ws;                // 40960 floats
    float* vsum = s + (size_t)B_TOT * JD;      // 40960 floats

    // ws is re-poisoned before every launch: zero s and vsum (328 KB)
    hipMemsetAsync(d_ws, 0, 2 * (size_t)B_TOT * JD * sizeof(float), stream);

    dim3 grid((B_TOT / BB) * ISPLIT), blk(NTHREADS);
    dim3 sgrid((B_TOT * JD) / 256), sblk(256);

    // iter 1 (c uniform = 0.1)
    iter_kernel<true><<<grid, blk, 0, stream>>>(x, Wt, nullptr, s);
    squash_kernel<<<sgrid, sblk, 0, stream>>>(s, vsum, out, 0);   // vsum = v1, s = 0
    // iter 2 (logits = u_hat . v1)
    iter_kernel<false><<<grid, blk, 0, stream>>>(x, Wt, vsum, s);
    squash_kernel<<<sgrid, sblk, 0, stream>>>(s, vsum, out, 0);   // vsum = v1+v2, s = 0
    // iter 3 (logits = u_hat . (v1+v2))
    iter_kernel<false><<<grid, blk, 0, stream>>>(x, Wt, vsum, s);
    squash_kernel<<<sgrid, sblk, 0, stream>>>(s, vsum, out, 1);   // out = v3
}